// Round 18
// baseline (121.180 us; speedup 1.0000x reference)
//
#include <hip/hip_runtime.h>
#include <cmath>

typedef float f4 __attribute__((ext_vector_type(4)));
typedef float f32x4 __attribute__((ext_vector_type(4)));
typedef short bf16x8 __attribute__((ext_vector_type(8)));
typedef unsigned short u16x8 __attribute__((ext_vector_type(8)));
typedef unsigned int u32x4 __attribute__((ext_vector_type(4)));

#define SCALEF 8.0f   // alpha/rank = 32/4

__device__ __forceinline__ unsigned cvtpk(float lo, float hi) {
    unsigned r;
    asm("v_cvt_pk_bf16_f32 %0, %1, %2" : "=v"(r) : "v"(lo), "v"(hi));
    return r;
}
__device__ __forceinline__ bf16x8 packA(const f4 a, const f4 b) {
    u32x4 u;
    u[0] = cvtpk(a[0], a[1]);
    u[1] = cvtpk(a[2], a[3]);
    u[2] = cvtpk(b[0], b[1]);
    u[3] = cvtpk(b[2], b[3]);
    return __builtin_bit_cast(bf16x8, u);
}

// ---- k0: prepack 12 weight rows into MFMA B-fragment stream (bf16) -------
// entry idx = s*64 + l: 8 bf16 = W[l&15][32s + (l>>4)*8 + j], 0-pad w>=12.
__global__ __launch_bounds__(256, 4) void k0_pack(
    const float* __restrict__ A_w,
    const float* __restrict__ router_w,
    unsigned short* __restrict__ wq)
{
    const int idx = blockIdx.x * 256 + threadIdx.x;   // 0..8191
    const int l = idx & 63, s = idx >> 6;
    const int w = l & 15;
    const int kb = 32 * s + (l >> 4) * 8;
    u16x8 o = (u16x8)0;
    if (w < 12) {
        const float* __restrict__ row = (w < 8)
            ? router_w + (size_t)w * 4096
            : A_w + (size_t)(w - 8) * 4096;
#pragma unroll
        for (int j = 0; j < 8; ++j) {
            union { float f; unsigned u; } a;
            a.f = row[kb + j];
            o[j] = (unsigned short)((a.u + 0x7FFFu + ((a.u >> 16) & 1u)) >> 16);
        }
    }
    *((u16x8*)wq + idx) = o;
}

struct Banks { f4 a0[4], a1[4]; u16x8 wb[4]; };
__device__ __forceinline__ void load4(Banks& B, const f4* __restrict__ xr,
                                      const u16x8* __restrict__ wr, int sb) {
#pragma unroll
    for (int i = 0; i < 4; ++i) {
        B.a0[i] = xr[8 * (sb + i)];
        B.a1[i] = xr[8 * (sb + i) + 1];
        B.wb[i] = wr[(sb + i) << 6];
    }
}
__device__ __forceinline__ void mfma4(f32x4& acc, const Banks& B) {
#pragma unroll
    for (int i = 0; i < 4; ++i)
        acc = __builtin_amdgcn_mfma_f32_16x16x32_bf16(
            packA(B.a0[i], B.a1[i]), __builtin_bit_cast(bf16x8, B.wb[i]),
            acc, 0, 0, 0);
}

// ---- main: 2048 blocks x 4 waves; block = 8-token tile (MFMA rows 8..15
// duplicate 0..7), K split 4-way. LB(256,4): allocator keeps ~64-reg live
// set (R12-grade pipeline); 4 blocks/CU resident, 2 generations/CU. --------
__global__ __launch_bounds__(256, 4) void tmlora_main(
    const float* __restrict__ x,
    const unsigned short* __restrict__ wq,
    const float* __restrict__ B_w,
    const float* __restrict__ expert_vectors,
    float* __restrict__ out)
{
    __shared__ float red[4][8][13];   // [wave][token][weight], padded
    __shared__ f4    hsh[8];          // h per token (SCALEF folded)

    const int tid  = threadIdx.x;
    const int wid  = tid >> 6, lane = tid & 63;
    const int tok0 = blockIdx.x * 8;
    const int s0   = wid * 32;          // wave's K-step base (K=1024 slice)

    // A: lane l covers row tok0+(l&7) (rows 8..15 duplicate), k-chunk (l>>4)*8
    const f4* __restrict__ xr =
        (const f4*)x + ((size_t)(tok0 + (lane & 7)) << 10) + ((lane >> 4) << 1);
    const u16x8* __restrict__ wr = (const u16x8*)wq + lane;

    Banks A, C;
    load4(A, xr, wr, s0);
    load4(C, xr, wr, s0 + 4);

    f32x4 acc = {0.f, 0.f, 0.f, 0.f};
#pragma unroll 1
    for (int it = 0; it < 4; ++it) {
        const int sb = s0 + it * 8;
        mfma4(acc, A);
        if (it < 3) load4(A, xr, wr, sb + 8);
        mfma4(acc, C);
        if (it < 3) load4(C, xr, wr, sb + 12);
    }

    // ---- per-wave C -> LDS; rows 8..15 are duplicates, lanes>=32 skip ----
    // lane holds scores[row=(lane>>4)*4+r][weight=lane&15]
    if (lane < 32) {
#pragma unroll
        for (int r = 0; r < 4; ++r)
            red[wid][(lane >> 4) * 4 + r][lane & 15] = acc[r];
    }
    __syncthreads();   // all K-loop loads consumed -> drain is free

    // ---- epilogue: threads 0..7, one token each ----
    if (tid < 8) {
        float s12[12];
#pragma unroll
        for (int w = 0; w < 12; ++w)
            s12[w] = red[0][tid][w] + red[1][tid][w] +
                     red[2][tid][w] + red[3][tid][w];

        int   idx[4];
        float val[4];
#pragma unroll
        for (int k = 0; k < 4; ++k) {
            int bi = 0; float bv = s12[0];
#pragma unroll
            for (int e = 1; e < 8; ++e)
                if (s12[e] > bv) { bv = s12[e]; bi = e; }
            idx[k] = bi; val[k] = bv;
#pragma unroll
            for (int e = 0; e < 8; ++e)
                if (e == bi) s12[e] = -INFINITY;   // static-index knockout
        }
        float ex[4], se = 0.f;
#pragma unroll
        for (int k = 0; k < 4; ++k) { ex[k] = expf(val[k] - val[0]); se += ex[k]; }
        const float inv = 1.f / se;
        float Et[4] = {0.f, 0.f, 0.f, 0.f};
#pragma unroll
        for (int k = 0; k < 4; ++k) {
            const float wgt = ex[k] * inv;
#pragma unroll
            for (int r = 0; r < 4; ++r)
                Et[r] = fmaf(wgt, expert_vectors[idx[k] * 4 + r], Et[r]);
        }
        f4 hv4;
#pragma unroll
        for (int r = 0; r < 4; ++r) {
            const float hv = s12[8 + r] + Et[r];
            hv4[r] = SCALEF * 0.5f * hv *
                     (1.f + erff(hv * 0.70710678118654752f));
        }
        hsh[tid] = hv4;
    }
    __syncthreads();

    // ---- store phase: 8 tokens x 1024 f4 chunks, B_w from L2 ----
    f4 hv[8];
#pragma unroll
    for (int t = 0; t < 8; ++t) hv[t] = hsh[t];

    const f4* __restrict__ b4 = (const f4*)B_w;
#pragma unroll
    for (int j = 0; j < 4; ++j) {
        const int c = tid + 256 * j;                 // f4-chunk within row
        const f4 B0 = b4[4 * c + 0], B1 = b4[4 * c + 1],
                 B2 = b4[4 * c + 2], B3 = b4[4 * c + 3];
#pragma unroll
        for (int t = 0; t < 8; ++t) {
            const f4 hh = hv[t];
            f4 v;
            v[0] = B0[0] * hh[0] + B0[1] * hh[1] + B0[2] * hh[2] + B0[3] * hh[3];
            v[1] = B1[0] * hh[0] + B1[1] * hh[1] + B1[2] * hh[2] + B1[3] * hh[3];
            v[2] = B2[0] * hh[0] + B2[1] * hh[1] + B2[2] * hh[2] + B2[3] * hh[3];
            v[3] = B3[0] * hh[0] + B3[1] * hh[1] + B3[2] * hh[2] + B3[3] * hh[3];
            __builtin_nontemporal_store(
                v, (f4*)out + (size_t)(tok0 + t) * 1024 + c);
        }
    }
}

extern "C" void kernel_launch(void* const* d_in, const int* in_sizes, int n_in,
                              void* d_out, int out_size, void* d_ws, size_t ws_size,
                              hipStream_t stream) {
    const float* x        = (const float*)d_in[0];
    const float* A_w      = (const float*)d_in[1];
    const float* B_w      = (const float*)d_in[2];
    const float* router_w = (const float*)d_in[3];
    const float* ev       = (const float*)d_in[4];
    float* out            = (float*)d_out;
    unsigned short* wq    = (unsigned short*)d_ws;   // 128 KB prepacked B-frags

    k0_pack<<<32, 256, 0, stream>>>(A_w, router_w, wq);
    tmlora_main<<<2048, 256, 0, stream>>>(x, wq, B_w, ev, out);
}

// Round 19
// 95.676 us; speedup vs baseline: 1.2666x; 1.2666x over previous
//
#include <hip/hip_runtime.h>
#include <cmath>

typedef float f4 __attribute__((ext_vector_type(4)));
typedef float f32x4 __attribute__((ext_vector_type(4)));
typedef short bf16x8 __attribute__((ext_vector_type(8)));
typedef unsigned short u16x8 __attribute__((ext_vector_type(8)));
typedef unsigned int u32x4 __attribute__((ext_vector_type(4)));

#define SCALEF 8.0f   // alpha/rank = 32/4

__device__ __forceinline__ unsigned cvtpk(float lo, float hi) {
    unsigned r;
    asm("v_cvt_pk_bf16_f32 %0, %1, %2" : "=v"(r) : "v"(lo), "v"(hi));
    return r;
}
__device__ __forceinline__ bf16x8 packA(const f4 a, const f4 b) {
    u32x4 u;
    u[0] = cvtpk(a[0], a[1]);
    u[1] = cvtpk(a[2], a[3]);
    u[2] = cvtpk(b[0], b[1]);
    u[3] = cvtpk(b[2], b[3]);
    return __builtin_bit_cast(bf16x8, u);
}

// ---- k0: prepack 12 weight rows into MFMA B-fragment stream (bf16) -------
// entry idx = s*64 + l: 8 bf16 = W[l&15][32s + (l>>4)*8 + j], 0-pad w>=12.
__global__ __launch_bounds__(256, 4) void k0_pack(
    const float* __restrict__ A_w,
    const float* __restrict__ router_w,
    unsigned short* __restrict__ wq)
{
    const int idx = blockIdx.x * 256 + threadIdx.x;   // 0..8191
    const int l = idx & 63, s = idx >> 6;
    const int w = l & 15;
    const int kb = 32 * s + (l >> 4) * 8;
    u16x8 o = (u16x8)0;
    if (w < 12) {
        const float* __restrict__ row = (w < 8)
            ? router_w + (size_t)w * 4096
            : A_w + (size_t)(w - 8) * 4096;
#pragma unroll
        for (int j = 0; j < 8; ++j) {
            union { float f; unsigned u; } a;
            a.f = row[kb + j];
            o[j] = (unsigned short)((a.u + 0x7FFFu + ((a.u >> 16) & 1u)) >> 16);
        }
    }
    *((u16x8*)wq + idx) = o;
}

struct Banks { f4 a0[4], a1[4]; u16x8 wb[4]; };
__device__ __forceinline__ void load4(Banks& B, const f4* __restrict__ xr,
                                      const u16x8* __restrict__ wr, int sb) {
#pragma unroll
    for (int i = 0; i < 4; ++i) {
        B.a0[i] = xr[8 * (sb + i)];
        B.a1[i] = xr[8 * (sb + i) + 1];
        B.wb[i] = wr[(sb + i) << 6];
    }
}
__device__ __forceinline__ void mfma4(f32x4& acc, const Banks& B) {
#pragma unroll
    for (int i = 0; i < 4; ++i)
        acc = __builtin_amdgcn_mfma_f32_16x16x32_bf16(
            packA(B.a0[i], B.a1[i]), __builtin_bit_cast(bf16x8, B.wb[i]),
            acc, 0, 0, 0);
}

// ---- main: 1024 blocks x 4 waves; block = 16-token tile, K split 4-way ----
__global__ __launch_bounds__(256, 4) void tmlora_main(
    const float* __restrict__ x,
    const unsigned short* __restrict__ wq,
    const float* __restrict__ B_w,
    const float* __restrict__ expert_vectors,
    float* __restrict__ out)
{
    __shared__ float red[4][16][17];   // [wave][token][weight], pad 17
    __shared__ f4    hsh[16];          // h per token (SCALEF folded)

    const int tid  = threadIdx.x;
    const int wid  = tid >> 6, lane = tid & 63;
    const int tok0 = blockIdx.x * 16;
    const int s0   = wid * 32;          // this wave's K-step base (K=1024)

    // A: lane l covers row tok0+(l&15), k-chunk (l>>4)*8 within each step
    const f4* __restrict__ xr =
        (const f4*)x + ((size_t)(tok0 + (lane & 15)) << 10) + ((lane >> 4) << 1);
    const u16x8* __restrict__ wr = (const u16x8*)wq + lane;

    // ---- K-loop: 32 steps, two banks of 4, 8 steps of loads in flight ----
    f4 a0[4], a1[4], c0[4], c1[4];
    u16x8 wb[4], wc[4];
#pragma unroll
    for (int i = 0; i < 4; ++i) {
        a0[i] = xr[8 * (s0 + i)];
        a1[i] = xr[8 * (s0 + i) + 1];
        wb[i] = wr[(s0 + i) << 6];
    }
#pragma unroll
    for (int i = 0; i < 4; ++i) {
        c0[i] = xr[8 * (s0 + 4 + i)];
        c1[i] = xr[8 * (s0 + 4 + i) + 1];
        wc[i] = wr[(s0 + 4 + i) << 6];
    }

    f32x4 acc = {0.f, 0.f, 0.f, 0.f};

#pragma unroll 1
    for (int it = 0; it < 4; ++it) {
        const int sb = s0 + it * 8;
#pragma unroll
        for (int i = 0; i < 4; ++i)
            acc = __builtin_amdgcn_mfma_f32_16x16x32_bf16(
                packA(a0[i], a1[i]), __builtin_bit_cast(bf16x8, wb[i]), acc, 0, 0, 0);
        if (it < 3) {
#pragma unroll
            for (int i = 0; i < 4; ++i) {
                a0[i] = xr[8 * (sb + 8 + i)];
                a1[i] = xr[8 * (sb + 8 + i) + 1];
                wb[i] = wr[(sb + 8 + i) << 6];
            }
        }
#pragma unroll
        for (int i = 0; i < 4; ++i)
            acc = __builtin_amdgcn_mfma_f32_16x16x32_bf16(
                packA(c0[i], c1[i]), __builtin_bit_cast(bf16x8, wc[i]), acc, 0, 0, 0);
        if (it < 3) {
#pragma unroll
            for (int i = 0; i < 4; ++i) {
                c0[i] = xr[8 * (sb + 12 + i)];
                c1[i] = xr[8 * (sb + 12 + i) + 1];
                wc[i] = wr[(sb + 12 + i) << 6];
            }
        }
    }

    // ---- per-wave C -> LDS (transposed); then block reduce ----
    // lane holds scores[token=(lane>>4)*4+r][weight=lane&15]
#pragma unroll
    for (int r = 0; r < 4; ++r)
        red[wid][(lane >> 4) * 4 + r][lane & 15] = acc[r];
    __syncthreads();   // K-loop loads all consumed; drain is free

    // ---- epilogue: threads 0..15, one token each ----
    if (tid < 16) {
        float s12[12];
#pragma unroll
        for (int w = 0; w < 12; ++w)
            s12[w] = red[0][tid][w] + red[1][tid][w] +
                     red[2][tid][w] + red[3][tid][w];

        int   idx[4];
        float val[4];
#pragma unroll
        for (int k = 0; k < 4; ++k) {
            int bi = 0; float bv = s12[0];
#pragma unroll
            for (int e = 1; e < 8; ++e)
                if (s12[e] > bv) { bv = s12[e]; bi = e; }
            idx[k] = bi; val[k] = bv;
#pragma unroll
            for (int e = 0; e < 8; ++e)
                if (e == bi) s12[e] = -INFINITY;   // static-index knockout
        }
        float ex[4], se = 0.f;
#pragma unroll
        for (int k = 0; k < 4; ++k) { ex[k] = expf(val[k] - val[0]); se += ex[k]; }
        const float inv = 1.f / se;
        float Et[4] = {0.f, 0.f, 0.f, 0.f};
#pragma unroll
        for (int k = 0; k < 4; ++k) {
            const float wgt = ex[k] * inv;
#pragma unroll
            for (int r = 0; r < 4; ++r)
                Et[r] = fmaf(wgt, expert_vectors[idx[k] * 4 + r], Et[r]);
        }
        f4 hv4;
#pragma unroll
        for (int r = 0; r < 4; ++r) {
            const float hv = s12[8 + r] + Et[r];
            hv4[r] = SCALEF * 0.5f * hv *
                     (1.f + erff(hv * 0.70710678118654752f));
        }
        hsh[tid] = hv4;
    }
    __syncthreads();

    // ---- phase 2: block-wide stores; 16 tokens x 1024 f4 chunks ----
    f4 hv[16];
#pragma unroll
    for (int t = 0; t < 16; ++t) hv[t] = hsh[t];

    const f4* __restrict__ b4 = (const f4*)B_w;
#pragma unroll
    for (int j = 0; j < 4; ++j) {
        const int c = tid + 256 * j;                 // f4-chunk within row
        const f4 B0 = b4[4 * c + 0], B1 = b4[4 * c + 1],
                 B2 = b4[4 * c + 2], B3 = b4[4 * c + 3];
#pragma unroll
        for (int t = 0; t < 16; ++t) {
            const f4 hh = hv[t];
            f4 v;
            v[0] = B0[0] * hh[0] + B0[1] * hh[1] + B0[2] * hh[2] + B0[3] * hh[3];
            v[1] = B1[0] * hh[0] + B1[1] * hh[1] + B1[2] * hh[2] + B1[3] * hh[3];
            v[2] = B2[0] * hh[0] + B2[1] * hh[1] + B2[2] * hh[2] + B2[3] * hh[3];
            v[3] = B3[0] * hh[0] + B3[1] * hh[1] + B3[2] * hh[2] + B3[3] * hh[3];
            __builtin_nontemporal_store(
                v, (f4*)out + (size_t)(tok0 + t) * 1024 + c);
        }
    }
}

extern "C" void kernel_launch(void* const* d_in, const int* in_sizes, int n_in,
                              void* d_out, int out_size, void* d_ws, size_t ws_size,
                              hipStream_t stream) {
    const float* x        = (const float*)d_in[0];
    const float* A_w      = (const float*)d_in[1];
    const float* B_w      = (const float*)d_in[2];
    const float* router_w = (const float*)d_in[3];
    const float* ev       = (const float*)d_in[4];
    float* out            = (float*)d_out;
    unsigned short* wq    = (unsigned short*)d_ws;   // 128 KB prepacked B-frags

    k0_pack<<<32, 256, 0, stream>>>(A_w, router_w, wq);
    tmlora_main<<<1024, 256, 0, stream>>>(x, wq, B_w, ev, out);
}